// Round 1
// baseline (319.433 us; speedup 1.0000x reference)
//
#include <hip/hip_runtime.h>

// ---- constants for this problem ----
// B=4, S=2048, E=1024, H=16, D=64, scale = D^-0.5 = 0.125, LN eps 1e-5
#define LOG2E 1.44269504088896340736f

typedef __attribute__((ext_vector_type(8)))  short  short8;
typedef __attribute__((ext_vector_type(4)))  float  f32x4;
typedef __attribute__((ext_vector_type(16))) float  f32x16;

// fp32 -> bf16, round-half-up (cheap, adequate: inputs are finite)
__device__ __forceinline__ unsigned short f2bf(float f) {
  unsigned u = __builtin_bit_cast(unsigned, f);
  return (unsigned short)((u + 0x8000u) >> 16);
}
// pack two fp32 -> bf16x2 in one u32 (lo = a, hi = b)
__device__ __forceinline__ unsigned pkbf(float a, float b) {
  unsigned ua = __builtin_bit_cast(unsigned, a);
  unsigned ub = __builtin_bit_cast(unsigned, b);
  return ((ub + 0x8000u) & 0xffff0000u) | ((ua + 0x8000u) >> 16);
}
// async global->LDS, 16B per lane; lds ptr must be wave-uniform base
__device__ __forceinline__ void gl16(const void* g, void* l) {
  __builtin_amdgcn_global_load_lds(
      (const __attribute__((address_space(1))) void*)g,
      (__attribute__((address_space(3))) void*)l, 16, 0, 0);
}

// ---------------- prep kernels ----------------

// x (fp32, 8M) -> bf16
__global__ __launch_bounds__(256) void prep_xb(const float* __restrict__ x,
                                               unsigned short* __restrict__ xb) {
  int i = blockIdx.x * 256 + threadIdx.x;      // grid 8192 -> 2M threads, x4 elems
  float4 v = ((const float4*)x)[i];
  ushort4 o;
  o.x = f2bf(v.x); o.y = f2bf(v.y); o.z = f2bf(v.z); o.w = f2bf(v.w);
  ((ushort4*)xb)[i] = o;
}

// W[e][f] fp32 -> Wt[f][e] bf16  (both rotation and entangle; z selects)
__global__ __launch_bounds__(256) void prep_wt(const float* __restrict__ R,
                                               const float* __restrict__ En,
                                               unsigned short* __restrict__ Rt,
                                               unsigned short* __restrict__ Et) {
  const float* src = blockIdx.z ? En : R;
  unsigned short* dst = blockIdx.z ? Et : Rt;
  __shared__ unsigned short t[64][65];
  int e0 = blockIdx.y * 64, f0 = blockIdx.x * 64;
  int tid = threadIdx.x;
  int r = tid >> 2, c4 = (tid & 3) * 16;
#pragma unroll
  for (int j = 0; j < 16; j += 4) {
    float4 v = *(const float4*)(src + (size_t)(e0 + r) * 1024 + f0 + c4 + j);
    t[c4 + j + 0][r] = f2bf(v.x);
    t[c4 + j + 1][r] = f2bf(v.y);
    t[c4 + j + 2][r] = f2bf(v.z);
    t[c4 + j + 3][r] = f2bf(v.w);
  }
  __syncthreads();
  short8 o0, o1;
#pragma unroll
  for (int j = 0; j < 8; j++) {
    o0[j] = (short)t[r][c4 + j];
    o1[j] = (short)t[r][c4 + 8 + j];
  }
  *(short8*)(dst + (size_t)(f0 + r) * 1024 + e0 + c4) = o0;
  *(short8*)(dst + (size_t)(f0 + r) * 1024 + e0 + c4 + 8) = o1;
}

// x[b][s][h*64+d] -> Vt[(bh*64+d)][s] bf16 (per-head transposed V)
__global__ __launch_bounds__(256) void prep_vt(const float* __restrict__ x,
                                               unsigned short* __restrict__ vt) {
  int bh = blockIdx.y, b = bh >> 4, h = bh & 15;
  int s0 = blockIdx.x * 64;
  __shared__ unsigned short t[64][65];   // [d][s]
  int tid = threadIdx.x;
  int r = tid >> 2, c4 = (tid & 3) * 16;
#pragma unroll
  for (int j = 0; j < 16; j += 4) {
    float4 v = *(const float4*)(x + (size_t)(b * 2048 + s0 + r) * 1024 + h * 64 + c4 + j);
    t[c4 + j + 0][r] = f2bf(v.x);
    t[c4 + j + 1][r] = f2bf(v.y);
    t[c4 + j + 2][r] = f2bf(v.z);
    t[c4 + j + 3][r] = f2bf(v.w);
  }
  __syncthreads();
  short8 o0, o1;
#pragma unroll
  for (int j = 0; j < 8; j++) {
    o0[j] = (short)t[r][c4 + j];
    o1[j] = (short)t[r][c4 + 8 + j];
  }
  *(short8*)(vt + (size_t)(bh * 64 + r) * 2048 + s0 + c4) = o0;
  *(short8*)(vt + (size_t)(bh * 64 + r) * 2048 + s0 + c4 + 8) = o1;
}

// ---------------- projection GEMM (m97 structure) ----------------
// C[8192][1024] = A[8192][1024] * W ; W supplied TRANSPOSED as Bw[f][e] bf16.
// 128x128 tile, BK=64, 4 waves in 2x2, 16x16x32 bf16 MFMA.
// LDS rows are 128B, XOR-swizzled: byte ^= (row&7)<<4 (conflict-free b128 reads).
__global__ __launch_bounds__(256) void gemm_qk(const unsigned short* __restrict__ A,
                                               const unsigned short* __restrict__ Bw,
                                               unsigned short* __restrict__ out,
                                               float scale) {
  int m0 = blockIdx.x * 128, n0 = blockIdx.y * 128;
  int tid = threadIdx.x;
  int w = tid >> 6, l = tid & 63;
  int wr = w >> 1, wc = w & 1;
  int l15 = l & 15, lq = l >> 4;

  __shared__ unsigned short As[128 * 64];
  __shared__ unsigned short Bs[128 * 64];

  f32x4 acc[4][4] = {};

  for (int k0 = 0; k0 < 1024; k0 += 64) {
    __syncthreads();
#pragma unroll
    for (int i = 0; i < 4; i++) {
      int row = i * 32 + (tid >> 3), ch = tid & 7;
      // source column pre-swizzled so linear LDS dest ends up swizzled (rule #21)
      gl16(A  + (size_t)(m0 + row) * 1024 + k0 + ((ch ^ (row & 7)) << 3),
           (char*)As + i * 4096 + w * 1024);
      gl16(Bw + (size_t)(n0 + row) * 1024 + k0 + ((ch ^ (row & 7)) << 3),
           (char*)Bs + i * 4096 + w * 1024);
    }
    __syncthreads();

    short8 af[4][2], bfr[4][2];
#pragma unroll
    for (int mf = 0; mf < 4; mf++)
#pragma unroll
      for (int kk = 0; kk < 2; kk++) {
        int row = wr * 64 + mf * 16 + l15;
        int kb2 = (kk * 32 + lq * 8) * 2;
        af[mf][kk] = *(const short8*)((const char*)As + row * 128 + (kb2 ^ ((row & 7) << 4)));
      }
#pragma unroll
    for (int nf = 0; nf < 4; nf++)
#pragma unroll
      for (int kk = 0; kk < 2; kk++) {
        int row = wc * 64 + nf * 16 + l15;
        int kb2 = (kk * 32 + lq * 8) * 2;
        bfr[nf][kk] = *(const short8*)((const char*)Bs + row * 128 + (kb2 ^ ((row & 7) << 4)));
      }
#pragma unroll
    for (int mf = 0; mf < 4; mf++)
#pragma unroll
      for (int nf = 0; nf < 4; nf++)
#pragma unroll
        for (int kk = 0; kk < 2; kk++)
          acc[mf][nf] = __builtin_amdgcn_mfma_f32_16x16x32_bf16(
              af[mf][kk], bfr[nf][kk], acc[mf][nf], 0, 0, 0);
  }

  // C/D layout (16x16): col = l&15, row = (l>>4)*4 + reg  [guide m89/m91]
#pragma unroll
  for (int mf = 0; mf < 4; mf++)
#pragma unroll
    for (int nf = 0; nf < 4; nf++)
#pragma unroll
      for (int r = 0; r < 4; r++) {
        int grow = m0 + wr * 64 + mf * 16 + lq * 4 + r;
        int gcol = n0 + wc * 64 + nf * 16 + l15;
        out[(size_t)grow * 1024 + gcol] = f2bf(acc[mf][nf][r] * scale);
      }
}

// ---------------- flash attention ----------------
// grid 1024 (flat, XCD-swizzled), 256 thr = 4 waves, wave owns 32 q-rows.
// Swapped QK^T: S^T = mfma(A=K_tile, B=Q) with 32x32x16 bf16.
// C/D layout (32x32): col = l&31, row = (reg&3) + 8*(reg>>2) + 4*(l>>5)  [m74/m101]
__global__ __launch_bounds__(256) void attn_k(const unsigned short* __restrict__ Q,
                                              const unsigned short* __restrict__ K,
                                              const unsigned short* __restrict__ VT,
                                              float* __restrict__ ctx) {
  int f = blockIdx.x;
  int bh = ((f >> 7) << 3) | (f & 7);   // cluster a head's q-tiles on one XCD
  int qt = (f >> 3) & 15;
  int b = bh >> 4, h = bh & 15;
  int q0 = qt * 128;
  int tid = threadIdx.x;
  int w = tid >> 6, l = tid & 63;
  int lh = l >> 5, l31 = l & 31;

  __shared__ unsigned short Kl[128 * 64];   // [t'][d], swizzled
  __shared__ unsigned short Vl[64 * 128];   // [d][t'], swizzled

  // Q fragments: B-operand, lane holds Q[q=l31][d = dk*16 + lh*8 + j]
  // (Q was pre-scaled by 0.125*log2e in the GEMM epilogue -> exp2 domain)
  int qrow = q0 + w * 32 + l31;
  const unsigned short* qp = Q + (size_t)(b * 2048 + qrow) * 1024 + h * 64;
  short8 qf[4];
#pragma unroll
  for (int dk = 0; dk < 4; dk++) qf[dk] = *(const short8*)(qp + dk * 16 + lh * 8);

  f32x16 cacc[2] = {};
  float mrun = -INFINITY, lsum = 0.f;

  for (int t0 = 0; t0 < 2048; t0 += 128) {
    __syncthreads();
    // stage K tile [128][64] bf16, rows 128B, swizzle (row&7)<<4 via source
#pragma unroll
    for (int i = 0; i < 4; i++) {
      int row = i * 32 + (tid >> 3), ch = tid & 7;
      gl16(K + (size_t)(b * 2048 + t0 + row) * 1024 + h * 64 + ((ch ^ (row & 7)) << 3),
           (char*)Kl + i * 4096 + w * 1024);
    }
    // stage V^T tile [64][128] bf16, rows 256B, swizzle (d&15)<<4 via source
#pragma unroll
    for (int i = 0; i < 4; i++) {
      int d = i * 16 + (tid >> 4), ch = tid & 15;
      gl16(VT + (size_t)(bh * 64 + d) * 2048 + t0 + ((ch ^ (d & 15)) << 3),
           (char*)Vl + i * 4096 + w * 1024);
    }
    __syncthreads();

    // S^T[t'][q]
    f32x16 sacc[4] = {};
#pragma unroll
    for (int tf = 0; tf < 4; tf++) {
#pragma unroll
      for (int dk = 0; dk < 4; dk++) {
        int row = tf * 32 + l31;
        int kb2 = (dk * 16 + lh * 8) * 2;
        short8 kf = *(const short8*)((const char*)Kl + row * 128 + (kb2 ^ ((row & 7) << 4)));
        sacc[tf] = __builtin_amdgcn_mfma_f32_32x32x16_bf16(kf, qf[dk], sacc[tf], 0, 0, 0);
      }
    }

    // online softmax over t' (log2 domain); lane owns q = l31, 64 of 128 t' here,
    // the other 64 live at lane^32.
    float tmax = -INFINITY;
#pragma unroll
    for (int tf = 0; tf < 4; tf++)
#pragma unroll
      for (int r = 0; r < 16; r++) tmax = fmaxf(tmax, sacc[tf][r]);
    tmax = fmaxf(tmax, __shfl_xor(tmax, 32, 64));
    float mnew = fmaxf(mrun, tmax);
    float alpha = exp2f(mrun - mnew);
    mrun = mnew;

    float rs = 0.f;
#pragma unroll
    for (int tf = 0; tf < 4; tf++)
#pragma unroll
      for (int r = 0; r < 16; r++) {
        float p = exp2f(sacc[tf][r] - mnew);
        sacc[tf][r] = p;
        rs += p;
      }
    rs += __shfl_xor(rs, 32, 64);
    lsum = lsum * alpha + rs;

    // rescale context acc rows by alpha[q_row] (broadcast via bpermute-shfl)
#pragma unroll
    for (int r = 0; r < 16; r++) {
      int rowq = (r & 3) + ((r >> 2) << 3) + (lh << 2);
      float ar = __shfl(alpha, rowq, 64);
      cacc[0][r] *= ar;
      cacc[1][r] *= ar;
    }

    // P -> A-operand fragments and PV accumulation
#pragma unroll
    for (int tf = 0; tf < 4; tf++) {
      short8 pa[2];
#pragma unroll
      for (int hf = 0; hf < 2; hf++) {
        int R0 = hf * 8;
        unsigned u0 = pkbf(sacc[tf][R0 + 0], sacc[tf][R0 + 1]);   // t' = T0 + 4h + {0,1}
        unsigned u1 = pkbf(sacc[tf][R0 + 2], sacc[tf][R0 + 3]);   // t' = T0 + 4h + {2,3}
        unsigned u2 = pkbf(sacc[tf][R0 + 4], sacc[tf][R0 + 5]);   // t' = T0+8+4h + {0,1}
        unsigned u3 = pkbf(sacc[tf][R0 + 6], sacc[tf][R0 + 7]);   // t' = T0+8+4h + {2,3}
        unsigned x0 = (unsigned)__shfl_xor((int)u0, 32, 64);
        unsigned x1 = (unsigned)__shfl_xor((int)u1, 32, 64);
        unsigned x2 = (unsigned)__shfl_xor((int)u2, 32, 64);
        unsigned x3 = (unsigned)__shfl_xor((int)u3, 32, 64);
        union { unsigned u[4]; short8 s; } wv;
        wv.u[0] = lh ? x2 : u0;   // k-local lh*8+{0,1}
        wv.u[1] = lh ? x3 : u1;   // k-local lh*8+{2,3}
        wv.u[2] = lh ? u2 : x0;   // k-local lh*8+{4,5}
        wv.u[3] = lh ? u3 : x1;   // k-local lh*8+{6,7}
        pa[hf] = wv.s;
      }
#pragma unroll
      for (int df = 0; df < 2; df++) {
#pragma unroll
        for (int kk = 0; kk < 2; kk++) {
          int d = df * 32 + l31;
          int tb2 = (tf * 32 + kk * 16 + lh * 8) * 2;
          short8 vf = *(const short8*)((const char*)Vl + d * 256 + (tb2 ^ ((d & 15) << 4)));
          cacc[df] = __builtin_amdgcn_mfma_f32_32x32x16_bf16(pa[kk], vf, cacc[df], 0, 0, 0);
        }
      }
    }
  }

  // epilogue: ctx[q][h*64 + d] = cacc / lsum
  float linv = 1.f / lsum;
#pragma unroll
  for (int r = 0; r < 16; r++) {
    int rowq = (r & 3) + ((r >> 2) << 3) + (lh << 2);
    float lr = __shfl(linv, rowq, 64);
    size_t base = (size_t)(b * 2048 + q0 + w * 32 + rowq) * 1024 + h * 64 + l31;
    ctx[base]      = cacc[0][r] * lr;
    ctx[base + 32] = cacc[1][r] * lr;
  }
}

// ---------------- residual + LayerNorm ----------------
__global__ __launch_bounds__(256) void ln_k(const float* __restrict__ ctx,
                                            const float* __restrict__ x,
                                            const float* __restrict__ wgt,
                                            const float* __restrict__ bgam,
                                            float* __restrict__ out) {
  int row = blockIdx.x;
  int tid = threadIdx.x;
  size_t base = (size_t)row * 1024 + tid * 4;
  float4 c = *(const float4*)(ctx + base);
  float4 xv = *(const float4*)(x + base);
  float4 y;
  y.x = c.x + xv.x; y.y = c.y + xv.y; y.z = c.z + xv.z; y.w = c.w + xv.w;
  float s  = y.x + y.y + y.z + y.w;
  float ss = y.x * y.x + y.y * y.y + y.z * y.z + y.w * y.w;
#pragma unroll
  for (int o = 32; o >= 1; o >>= 1) {
    s  += __shfl_xor(s, o, 64);
    ss += __shfl_xor(ss, o, 64);
  }
  __shared__ float sm[8];
  if ((tid & 63) == 0) { sm[(tid >> 6) * 2] = s; sm[(tid >> 6) * 2 + 1] = ss; }
  __syncthreads();
  s  = sm[0] + sm[2] + sm[4] + sm[6];
  ss = sm[1] + sm[3] + sm[5] + sm[7];
  float mu = s * (1.f / 1024.f);
  float var = ss * (1.f / 1024.f) - mu * mu;
  float rstd = rsqrtf(var + 1e-5f);
  float4 wv = *(const float4*)(wgt + tid * 4);
  float4 bv = *(const float4*)(bgam + tid * 4);
  float4 o4;
  o4.x = (y.x - mu) * rstd * wv.x + bv.x;
  o4.y = (y.y - mu) * rstd * wv.y + bv.y;
  o4.z = (y.z - mu) * rstd * wv.z + bv.z;
  o4.w = (y.w - mu) * rstd * wv.w + bv.w;
  *(float4*)(out + base) = o4;
}

// ---------------- launch ----------------
extern "C" void kernel_launch(void* const* d_in, const int* in_sizes, int n_in,
                              void* d_out, int out_size, void* d_ws, size_t ws_size,
                              hipStream_t stream) {
  (void)in_sizes; (void)n_in; (void)out_size; (void)ws_size;
  const float* R  = (const float*)d_in[0];   // rotation_params (E,E)
  const float* En = (const float*)d_in[1];   // entangle_params (E,E)
  const float* x  = (const float*)d_in[2];   // inputs (B,S,E)
  const float* lw = (const float*)d_in[3];   // ln_weight
  const float* lb = (const float*)d_in[4];   // ln_bias
  float* out = (float*)d_out;

  char* ws = (char*)d_ws;
  unsigned short* xb  = (unsigned short*)(ws);                       // 16 MB bf16 x
  unsigned short* qb  = (unsigned short*)(ws + (size_t)(16u << 20)); // 16 MB Q
  unsigned short* kb  = (unsigned short*)(ws + (size_t)(32u << 20)); // 16 MB K
  unsigned short* vt  = (unsigned short*)(ws + (size_t)(48u << 20)); // 16 MB V^T
  float*          ctx = (float*)(ws + (size_t)(64u << 20));          // 32 MB context
  unsigned short* rt  = (unsigned short*)(ws + (size_t)(96u << 20)); //  2 MB R^T
  unsigned short* et  = (unsigned short*)(ws + (size_t)(98u << 20)); //  2 MB E^T

  prep_xb<<<8192, 256, 0, stream>>>(x, xb);
  prep_wt<<<dim3(16, 16, 2), 256, 0, stream>>>(R, En, rt, et);
  prep_vt<<<dim3(32, 64), 256, 0, stream>>>(x, vt);
  // Q gets softmax scale folded in (0.125 * log2e -> exp2-domain softmax)
  gemm_qk<<<dim3(64, 8), 256, 0, stream>>>(xb, rt, qb, 0.125f * LOG2E);
  gemm_qk<<<dim3(64, 8), 256, 0, stream>>>(xb, et, kb, 1.0f);
  attn_k<<<1024, 256, 0, stream>>>(qb, kb, vt, ctx);
  ln_k<<<8192, 256, 0, stream>>>(ctx, x, lw, lb, out);
}